// Round 13
// baseline (375.510 us; speedup 1.0000x reference)
//
#include <hip/hip_runtime.h>
#include <math.h>

#define P_TOT 65536   // 16*64*64 spatial positions
#define CH    128     // channels
#define NHEAD 8
#define KD    4
#define KH    8
#define KW    8
#define NJ    256     // KD*KH*KW keys per head

typedef unsigned short u16;
typedef unsigned int   u32;
typedef __attribute__((ext_vector_type(8))) short frag8;   // bf16x8 (4 VGPRs)
typedef __attribute__((ext_vector_type(4))) float f32x4;   // MFMA C/D

__device__ inline u16 bf16r(float a) {                     // RTNE round
    u32 ua = __float_as_uint(a);
    return (u16)((ua + 0x7fff + ((ua >> 16) & 1)) >> 16);
}
__device__ inline float bf16f(u16 h) {
    return __uint_as_float(((u32)h) << 16);
}
__device__ inline u32 packhl(float v) {                    // hi | lo<<16
    u16 hh = bf16r(v);
    u16 ll = bf16r(v - bf16f(hh));
    return (u32)hh | ((u32)ll << 16);
}

// ---- LayerNorm, 64p x 128c tile; emits bf16 hi/lo PLANES xn_hi/xn_lo[p][c] --
__global__ __launch_bounds__(256) void k_ln(const float* __restrict__ x,
                                            const float* __restrict__ g,
                                            const float* __restrict__ b,
                                            u16* __restrict__ xn_hi,
                                            u16* __restrict__ xn_lo) {
    __shared__ u32 buf[64 * 131];         // 33.5 KB: xt (32 KB floats) then tr
    __shared__ float red[8 * 64];
    __shared__ float stat[2 * 64];
    float* xt = (float*)buf;              // [c][pp] 128x64
    int t  = threadIdx.x;
    int p0 = blockIdx.x * 64;
    #pragma unroll
    for (int r = 0; r < 8; ++r) {         // load tile: 2048 float4 chunks
        int id = t + 256 * r;
        int c = id >> 4, q4 = id & 15;
        *(float4*)(xt + c * 64 + q4 * 4) =
            *(const float4*)(x + (size_t)c * P_TOT + p0 + q4 * 4);
    }
    __syncthreads();
    int pp = t & 63, part = t >> 6;
    float sum = 0.f, ssq = 0.f;
    for (int ci = 0; ci < 32; ++ci) {
        float v = xt[(part * 32 + ci) * 64 + pp];
        sum += v; ssq += v * v;
    }
    red[part * 64 + pp] = sum;
    red[256 + part * 64 + pp] = ssq;
    __syncthreads();
    if (t < 64) {
        float s = red[t] + red[64 + t] + red[128 + t] + red[192 + t];
        float q = red[256 + t] + red[320 + t] + red[384 + t] + red[448 + t];
        float mean = s * (1.f / CH);
        float var  = q * (1.f / CH) - mean * mean;
        stat[t] = mean;
        stat[64 + t] = 1.f / sqrtf(var + 1e-5f);
    }
    __syncthreads();
    float mean = stat[pp], inv = stat[64 + pp];
    u32 pk[32];
    for (int ci = 0; ci < 32; ++ci) {
        int c = part * 32 + ci;
        float v  = xt[c * 64 + pp];
        float xn = (v - mean) * inv * g[c] + b[c];
        pk[ci] = packhl(xn);
    }
    __syncthreads();                      // all xt reads done; reuse buf as tr
    u32* tr = buf;                        // [pp][c] stride 131
    for (int ci = 0; ci < 32; ++ci)
        tr[pp * 131 + part * 32 + ci] = pk[ci];
    __syncthreads();
    #pragma unroll
    for (int r = 0; r < 8; ++r) {         // store: 2048 chunks -> 2 planes
        int id = t + 256 * r;
        int pr = id >> 5, ch = id & 31;
        const u32* srcp = tr + pr * 131 + ch * 4;
        u32 v0 = srcp[0], v1 = srcp[1], v2 = srcp[2], v3 = srcp[3];
        uint2 hv, lv;
        hv.x = __builtin_amdgcn_perm(v1, v0, 0x05040100);   // low16 pair
        hv.y = __builtin_amdgcn_perm(v3, v2, 0x05040100);
        lv.x = __builtin_amdgcn_perm(v1, v0, 0x07060302);   // high16 pair
        lv.y = __builtin_amdgcn_perm(v3, v2, 0x07060302);
        size_t off = (size_t)(p0 + pr) * 128 + ch * 4;
        *(uint2*)(xn_hi + off) = hv;
        *(uint2*)(xn_lo + off) = lv;
    }
}

// ---- split weights into bf16 hi/lo planes ----------------------------------
__global__ __launch_bounds__(256) void k_wsplit(const float* __restrict__ wqkv,
                                                const float* __restrict__ wout,
                                                u16* __restrict__ w_hi,
                                                u16* __restrict__ w_lo,
                                                u16* __restrict__ w2_hi,
                                                u16* __restrict__ w2_lo) {
    int id = blockIdx.x * 256 + threadIdx.x;   // 0..98303
    if (id < 65536) {
        float v = wqkv[id];
        u16 hh = bf16r(v);
        w_hi[id] = hh; w_lo[id] = bf16r(v - bf16f(hh));
    } else {
        int j = id - 65536;                    // 128*256 wout
        float v = wout[j];
        u16 hh = bf16r(v);
        w2_hi[j] = hh; w2_lo[j] = bf16r(v - bf16f(hh));
    }
}

// ---- MFMA qkv GEMM (R6 tiling) + R12 bf16 k-store via LDS transpose --------
// R10 verified the bf16 k-plane is numerics-safe (run PASSED, absmax
// unchanged) and cuts WRITE 139->106 MB; it failed only because the direct
// ushort4 epilogue bloated VGPR 104->132. R12 routes the k-store through an
// LDS transpose identical in structure to the q-path's qtb epilogue (which
// co-exists with VGPR=104): scalar bf16r writes into kt[ol][pl] (stride 136
// u16: 16B-aligned rows, <=2-way write conflicts = free), barrier, then
// 2048 coalesced uint4 streaming stores.
__global__ __launch_bounds__(256) void k_gemm_qkv(const u16* __restrict__ xn_hi,
                                                  const u16* __restrict__ xn_lo,
                                                  const u16* __restrict__ w_hi,
                                                  const u16* __restrict__ w_lo,
                                                  u16* __restrict__ kbf,
                                                  u16* __restrict__ qT,
                                                  float* __restrict__ pdh,
                                                  float* __restrict__ qpwp) {
    __shared__ u16 smem[4 * 128 * 64];    // 64 KB
    u16* a_hi = smem;
    u16* a_lo = smem + 8192;
    u16* b_hi = smem + 16384;
    u16* b_lo = smem + 24576;
    int t    = threadIdx.x;
    int lane = t & 63, wave = t >> 6;
    int wp = wave & 1, wo = wave >> 1;
    int m = lane & 15, quad = lane >> 4;
    int p0 = blockIdx.x * 128;
    int o0 = blockIdx.y * 128;
    f32x4 acc[4][4] = {};
    for (int k0 = 0; k0 < 128; k0 += 64) {
        __syncthreads();
        #pragma unroll
        for (int r = 0; r < 4; ++r) {      // 1024 granule slots per buffer
            int id  = t + 256 * r;
            int row = id >> 3, gg = id & 7;
            int gs  = gg ^ (row & 7);      // pre-swizzled source granule
            int dst = row * 64 + gg * 8;   // linear LDS dest
            size_t sa = (size_t)(p0 + row) * 128 + k0 + gs * 8;
            size_t sb = (size_t)(o0 + row) * 128 + k0 + gs * 8;
            *(uint4*)(a_hi + dst) = *(const uint4*)(xn_hi + sa);
            *(uint4*)(a_lo + dst) = *(const uint4*)(xn_lo + sa);
            *(uint4*)(b_hi + dst) = *(const uint4*)(w_hi + sb);
            *(uint4*)(b_lo + dst) = *(const uint4*)(w_lo + sb);
        }
        __syncthreads();
        #pragma unroll
        for (int ks = 0; ks < 2; ++ks) {
            frag8 ah[4], al[4], bh[4], bl[4];
            #pragma unroll
            for (int i = 0; i < 4; ++i) {
                int row = wp * 64 + i * 16 + m;
                int gg  = (ks * 4 + quad) ^ (row & 7);
                ah[i] = *(const frag8*)(a_hi + row * 64 + gg * 8);
                al[i] = *(const frag8*)(a_lo + row * 64 + gg * 8);
            }
            #pragma unroll
            for (int j = 0; j < 4; ++j) {
                int row = wo * 64 + j * 16 + m;
                int gg  = (ks * 4 + quad) ^ (row & 7);
                bh[j] = *(const frag8*)(b_hi + row * 64 + gg * 8);
                bl[j] = *(const frag8*)(b_lo + row * 64 + gg * 8);
            }
            #pragma unroll
            for (int i = 0; i < 4; ++i)
                #pragma unroll
                for (int j = 0; j < 4; ++j) {
                    acc[i][j] = __builtin_amdgcn_mfma_f32_16x16x32_bf16(ah[i], bh[j], acc[i][j], 0, 0, 0);
                    acc[i][j] = __builtin_amdgcn_mfma_f32_16x16x32_bf16(ah[i], bl[j], acc[i][j], 0, 0, 0);
                    acc[i][j] = __builtin_amdgcn_mfma_f32_16x16x32_bf16(al[i], bh[j], acc[i][j], 0, 0, 0);
                }
        }
    }
    // ---- fused l2-norm: group jg covers o rows [o0+wo*64+jg*32, +32) -------
    #pragma unroll
    for (int i = 0; i < 4; ++i) {
        #pragma unroll
        for (int jg = 0; jg < 2; ++jg) {
            f32x4 s;
            #pragma unroll
            for (int r = 0; r < 4; ++r)
                s[r] = acc[i][2 * jg][r] * acc[i][2 * jg][r]
                     + acc[i][2 * jg + 1][r] * acc[i][2 * jg + 1][r];
            #pragma unroll
            for (int mask = 1; mask <= 8; mask <<= 1) {
                s[0] += __shfl_xor(s[0], mask, 64);
                s[1] += __shfl_xor(s[1], mask, 64);
                s[2] += __shfl_xor(s[2], mask, 64);
                s[3] += __shfl_xor(s[3], mask, 64);
            }
            #pragma unroll
            for (int r = 0; r < 4; ++r) {
                float inv = 1.f / fmaxf(sqrtf(s[r]), 1e-12f);
                acc[i][2 * jg][r]     *= inv;
                acc[i][2 * jg + 1][r] *= inv;
            }
        }
    }
    // ---- fused probes (direct stores only) ---------------------------------
    int pb = blockIdx.x;
    int d  = pb >> 5;
    int hh = (2 * pb + wp) & 63;
    bool isQ = (o0 < 256);
    {
        float sj[4];
        #pragma unroll
        for (int j = 0; j < 4; ++j) {
            float s = 0.f;
            #pragma unroll
            for (int i = 0; i < 4; ++i)
                #pragma unroll
                for (int r = 0; r < 4; ++r)
                    s += fabsf(acc[i][j][r]);
            sj[j] = s;
        }
        #pragma unroll
        for (int j = 0; j < 4; ++j) {      // reduce over quad (lanes ^16,^32)
            sj[j] += __shfl_xor(sj[j], 16, 64);
            sj[j] += __shfl_xor(sj[j], 32, 64);
        }
        if (quad == 0) {
            #pragma unroll
            for (int j = 0; j < 4; ++j) {
                int o = o0 + wo * 64 + j * 16 + m;
                pdh[((size_t)o * 16 + d) * 64 + hh] = sj[j];   // unique owner
            }
        }
    }
    if (isQ) {
        // ---- qpw partial: LDS [w][ol] stride 129, wp0 writes / wp1 adds ----
        float* qw = (float*)smem;
        __syncthreads();                   // MFMA smem reads all done
        if (wp == 0) {
            #pragma unroll
            for (int j = 0; j < 4; ++j) {
                int ol = wo * 64 + j * 16 + m;
                #pragma unroll
                for (int i = 0; i < 4; ++i)
                    #pragma unroll
                    for (int r = 0; r < 4; ++r)
                        qw[(i * 16 + quad * 4 + r) * 129 + ol] = fabsf(acc[i][j][r]);
            }
        }
        __syncthreads();
        if (wp == 1) {
            #pragma unroll
            for (int j = 0; j < 4; ++j) {
                int ol = wo * 64 + j * 16 + m;
                #pragma unroll
                for (int i = 0; i < 4; ++i)
                    #pragma unroll
                    for (int r = 0; r < 4; ++r)
                        qw[(i * 16 + quad * 4 + r) * 129 + ol] += fabsf(acc[i][j][r]);
            }
        }
        __syncthreads();
        // private partial tile, coalesced store: dst[ol*64+w] = qw[w*129+ol]
        float* dstp = qpwp + ((size_t)(blockIdx.y * 512 + pb)) * 8192;
        #pragma unroll
        for (int ri = 0; ri < 32; ++ri) {
            int id = t + 256 * ri;         // id = ol*64 + w
            int ol = id >> 6, w = id & 63;
            dstp[id] = qw[w * 129 + ol];
        }
        // ---- qT via LDS transpose + coalesced uint4 stores -----------------
        __syncthreads();                   // qw reads done; reuse smem as qtb
        u16* qtb = smem;                   // [grp][128 pl][stride 40]: 40 KB
        #pragma unroll
        for (int i = 0; i < 4; ++i)
            #pragma unroll
            for (int j = 0; j < 4; ++j) {
                int grp = wo * 2 + (j >> 1);
                int c   = (j & 1) * 16 + m;
                #pragma unroll
                for (int r = 0; r < 4; ++r) {
                    int pl = wp * 64 + i * 16 + quad * 4 + r;
                    qtb[grp * 5120 + pl * 40 + c] = bf16r(acc[i][j][r]);
                }
            }
        __syncthreads();
        int gbase = o0 >> 5;
        #pragma unroll
        for (int ri = 0; ri < 8; ++ri) {
            int id = t + 256 * ri;         // 2048 uint4 = 4grp x 128pl x 4cq
            int grp = id >> 9, rem = id & 511;
            int pl = rem >> 2, cq = rem & 3;
            uint4 v = *(const uint4*)(qtb + grp * 5120 + pl * 40 + cq * 8);
            *(uint4*)(qT + ((size_t)(gbase + grp) * P_TOT + p0 + pl) * 32 + cq * 8) = v;
        }
    } else {
        // ---- k rows: bf16 via LDS transpose + coalesced uint4 stores -------
        // kt[ol 0..127][pl 0..127], stride 136 u16 (272B rows, 16B-aligned).
        u16* kt = smem;                    // 34.8 KB
        __syncthreads();                   // MFMA smem reads all done
        #pragma unroll
        for (int i = 0; i < 4; ++i)
            #pragma unroll
            for (int j = 0; j < 4; ++j) {
                int ol = wo * 64 + j * 16 + m;
                #pragma unroll
                for (int r = 0; r < 4; ++r) {
                    int pl = wp * 64 + i * 16 + quad * 4 + r;
                    kt[ol * 136 + pl] = bf16r(acc[i][j][r]);
                }
            }
        __syncthreads();
        #pragma unroll
        for (int ri = 0; ri < 8; ++ri) {
            int id = t + 256 * ri;         // 2048 uint4 = 128 ol x 16 pq
            int ol = id >> 4, pq = id & 15;
            uint4 v = *(const uint4*)(kt + ol * 136 + pq * 8);
            *(uint4*)(kbf + (size_t)(o0 - 256 + ol) * P_TOT + p0 + pq * 8) = v;
        }
    }
}

// ---- pd[o][d] = sum_h pdh[o][d][h] (2 MB read, trivial) --------------------
__global__ __launch_bounds__(256) void k_pd(const float* __restrict__ pdh,
                                            float* __restrict__ pd) {
    int gid = blockIdx.x * 256 + threadIdx.x;   // 0..8191
    const float* src = pdh + (size_t)gid * 64;
    float s = 0.f;
    #pragma unroll
    for (int h = 0; h < 64; ++h) s += src[h];
    pd[gid] = s;
}

// ---- qpw[o][w] = sum_pb qpwp[part][ (o&127)*64 + w ] (33.5 MB read) --------
__global__ __launch_bounds__(256) void k_qpw(const float* __restrict__ qpwp,
                                             float* __restrict__ qpw) {
    int o = blockIdx.x;                    // 0..255
    int t = threadIdx.x;
    int w = t & 63, sub = t >> 6;
    int y = o >> 7, ol = o & 127;
    __shared__ float red[256];
    float s = 0.f;
    #pragma unroll 8
    for (int pb = sub * 128; pb < sub * 128 + 128; ++pb)
        s += qpwp[((size_t)(y * 512 + pb)) * 8192 + ol * 64 + w];
    red[t] = s;
    __syncthreads();
    if (t < 64) qpw[o * 64 + w] = red[w] + red[64 + w] + red[128 + w] + red[192 + w];
}

// ---------------- top-k kernels ----------------
__global__ __launch_bounds__(64) void k_topk_d(const float* __restrict__ pd,
                                               int* __restrict__ idx_d) {
    int h = blockIdx.x, t = threadIdx.x;
    __shared__ float sc[16];
    if (t < 16) {
        float s = 0.f;
        for (int c = 0; c < 32; ++c)
            s += pd[(h * 32 + c) * 16 + t] * pd[(256 + h * 32 + c) * 16 + t];
        sc[t] = s;
    }
    __syncthreads();
    if (t == 0) {
        bool used[16] = {};
        for (int r = 0; r < KD; ++r) {
            int best = 0; float bv = -1e30f;
            for (int i = 0; i < 16; ++i)
                if (!used[i] && sc[i] > bv) { bv = sc[i]; best = i; }
            used[best] = true;
            idx_d[h * KD + r] = best;
        }
    }
}

__global__ __launch_bounds__(256) void k_topk_h(const float* __restrict__ pdh,
                                                const int* __restrict__ idx_d,
                                                int* __restrict__ idx_h) {
    int h = blockIdx.x, t = threadIdx.x;
    int tq = t & 63, cg = t >> 6;
    __shared__ float sc2[4][64];
    __shared__ float sc[64];
    int ds[KD];
    #pragma unroll
    for (int i = 0; i < KD; ++i) ds[i] = idx_d[h * KD + i];
    float partial = 0.f;
    for (int ci = 0; ci < 8; ++ci) {
        int c  = cg * 8 + ci;
        int oq = h * 32 + c, ok = 256 + h * 32 + c;
        float qp = 0.f;                    // qph inline: sum pdh over all d
        #pragma unroll
        for (int dq = 0; dq < 16; ++dq)
            qp += pdh[((size_t)oq * 16 + dq) * 64 + tq];
        float kp = 0.f;
        #pragma unroll
        for (int i = 0; i < KD; ++i) kp += pdh[((size_t)ok * 16 + ds[i]) * 64 + tq];
        partial += qp * kp;
    }
    sc2[cg][tq] = partial;
    __syncthreads();
    if (t < 64) sc[t] = sc2[0][t] + sc2[1][t] + sc2[2][t] + sc2[3][t];
    __syncthreads();
    if (t == 0) {
        bool used[64] = {};
        for (int r = 0; r < KH; ++r) {
            int best = 0; float bv = -1e30f;
            for (int i = 0; i < 64; ++i)
                if (!used[i] && sc[i] > bv) { bv = sc[i]; best = i; }
            used[best] = true;
            idx_h[h * KH + r] = best;
        }
    }
}

__global__ __launch_bounds__(64) void k_probe_w(const u16* __restrict__ kbf,
                                                const int* __restrict__ idx_d,
                                                const int* __restrict__ idx_h,
                                                float* __restrict__ kpw) {
    int o2 = blockIdx.x;
    int w  = threadIdx.x;
    int h  = o2 >> 5;
    const u16* src = kbf + (size_t)o2 * P_TOT;
    float s = 0.f;
    for (int i = 0; i < KD; ++i) {
        int pb = idx_d[h * KD + i] * 4096;
        for (int j = 0; j < KH; ++j)
            s += fabsf(bf16f(src[pb + idx_h[h * KH + j] * 64 + w]));
    }
    kpw[o2 * 64 + w] = s;
}

__global__ __launch_bounds__(256) void k_topk_w(const float* __restrict__ qpw,
                                                const float* __restrict__ kpw,
                                                int* __restrict__ idx_w) {
    int h = blockIdx.x, t = threadIdx.x;
    int tq = t & 63, cg = t >> 6;
    __shared__ float sc2[4][64];
    __shared__ float sc[64];
    float partial = 0.f;
    for (int ci = 0; ci < 8; ++ci) {
        int c  = cg * 8 + ci;
        int oq = h * 32 + c;
        partial += qpw[oq * 64 + tq] * kpw[(h * 32 + c) * 64 + tq];
    }
    sc2[cg][tq] = partial;
    __syncthreads();
    if (t < 64) sc[t] = sc2[0][t] + sc2[1][t] + sc2[2][t] + sc2[3][t];
    __syncthreads();
    if (t == 0) {
        bool used[64] = {};
        for (int r = 0; r < KW; ++r) {
            int best = 0; float bv = -1e30f;
            for (int i = 0; i < 64; ++i)
                if (!used[i] && sc[i] > bv) { bv = sc[i]; best = i; }
            used[best] = true;
            idx_w[h * KW + r] = best;
        }
    }
}

// ------- gather pruned k (bf16 [h][j][32]) + recompute v (bf16 [h][c][256]) ---
// k is already bf16 in kbf -- kb gather is a pure 2B copy (bitwise identical
// to the old bf16r(fp32) since bf16r was applied in the gemm epilogue).
// vT j-axis is stored PERMUTED so k_attn's PV B-operand comes straight from
// the QK^T result registers. Mapping: value for key slot j lands at
// pos = (j&0xE0) | ((j&0x0C)<<1) | ((j&0x10)>>2) | (j&3).
__global__ __launch_bounds__(64) void k_gather(const u16* __restrict__ kbf,
                                               const u16* __restrict__ xn_hi,
                                               const u16* __restrict__ xn_lo,
                                               const float* __restrict__ wqkv,
                                               const int* __restrict__ idx_d,
                                               const int* __restrict__ idx_h,
                                               const int* __restrict__ idx_w,
                                               u16* __restrict__ kb,
                                               u16* __restrict__ vT) {
    int h  = blockIdx.x;          // 0..7
    int jb = blockIdx.y;          // 0..127
    int t  = threadIdx.x;         // 0..63
    int j  = jb * 2 + (t >> 5);
    int c  = t & 31;
    int di = j >> 6, hi = (j >> 3) & 7, wi = j & 7;
    int p  = idx_d[h * KD + di] * 4096 + idx_h[h * KH + hi] * 64 + idx_w[h * KW + wi];
    kb[(h * NJ + j) * 32 + c] = kbf[(size_t)(h * 32 + c) * P_TOT + p];
    const float* wr = wqkv + (512 + h * 32 + c) * CH;
    const u16* xh = xn_hi + (size_t)p * 128;
    const u16* xl = xn_lo + (size_t)p * 128;
    float acc = 0.f;
    for (int cc = 0; cc < CH; ++cc) {
        float v = bf16f(xh[cc]) + bf16f(xl[cc]);
        acc += wr[cc] * v;
    }
    int pos = (j & 0xE0) | ((j & 0x0C) << 1) | ((j & 0x10) >> 2) | (j & 3);
    vT[((size_t)h * 32 + c) * NJ + pos] = bf16r(acc);
}

// ------- MFMA flash attention, R2: K/V staged in LDS, reused 16x ------------
__device__ inline frag8 mk_frag(uint2 a, uint2 b) {
    union { u32 u[4]; frag8 f; } v;
    v.u[0] = a.x; v.u[1] = a.y; v.u[2] = b.x; v.u[3] = b.y;
    return v.f;
}

__global__ __launch_bounds__(256) void k_attn(const u16* __restrict__ qT,
                                              const u16* __restrict__ kb,
                                              const u16* __restrict__ vT,
                                              u32* __restrict__ attn_pk) {
    __shared__ u16 sK[256 * 32];        // [j][c] linear, 16 KB
    __shared__ u16 sV[32 * 264];        // [row][pos], stride 264 u16, 16.5 KB
    int h    = blockIdx.x >> 8;         // 2048 blocks: 8 heads x 256 chunks
    int pc   = blockIdx.x & 255;
    int wave = threadIdx.x >> 6;
    int lane = threadIdx.x & 63;
    int m    = lane & 15;
    int quad = lane >> 4;
    int t    = threadIdx.x;

    int qbase = pc * 256 + wave * 64;   // this wave's 64 queries
    frag8 bq[4];
    #pragma unroll
    for (int i = 0; i < 4; ++i)
        bq[i] = *(const frag8*)(qT + ((size_t)h * P_TOT + qbase + i * 16 + m) * 32 + quad * 8);

    const uint4* kg  = (const uint4*)(kb + (size_t)h * NJ * 32);
    uint4*       sKg = (uint4*)sK;
    #pragma unroll
    for (int r = 0; r < 4; ++r)
        sKg[t + 256 * r] = kg[t + 256 * r];
    const uint4* vg = (const uint4*)(vT + (size_t)h * 32 * NJ);
    #pragma unroll
    for (int r = 0; r < 4; ++r) {
        int g2 = t + 256 * r;
        int row = g2 >> 5, col = g2 & 31;
        *(uint4*)(sV + row * 264 + col * 8) = vg[g2];
    }
    __syncthreads();

    f32x4 zero = {0.f, 0.f, 0.f, 0.f};
    #pragma unroll
    for (int tile = 0; tile < 4; ++tile) {
        int p = qbase + tile * 16 + m;
        float den = 0.f;
        uint2 pk[16];
        #pragma unroll
        for (int tt = 0; tt < 16; ++tt) {
            frag8 ak = *(const frag8*)(sK + (tt * 16 + m) * 32 + quad * 8);
            f32x4 st = __builtin_amdgcn_mfma_f32_16x16x32_bf16(ak, bq[tile], zero, 0, 0, 0);
            float e0 = __expf(st[0]);
            float e1 = __expf(st[1]);
            float e2 = __expf(st[2]);
            float e3 = __expf(st[3]);
            den += (e0 + e1) + (e2 + e3);
            pk[tt].x = __builtin_amdgcn_perm(__float_as_uint(e1), __float_as_uint(e0), 0x07060302);
            pk[tt].y = __builtin_amdgcn_perm(__float_as_uint(e3), __float_as_uint(e2), 0x07060302);
        }
        den += __shfl_xor(den, 16, 64);
        den += __shfl_xor(den, 32, 64);

        f32x4 a0e = zero, a0o = zero, a1e = zero, a1o = zero;
        #pragma unroll
        for (int jc = 0; jc < 8; jc += 2) {
            frag8 bp0  = mk_frag(pk[2 * jc],     pk[2 * jc + 1]);
            frag8 bp1  = mk_frag(pk[2 * jc + 2], pk[2 * jc + 3]);
            frag8 av00 = *(const frag8*)(sV + m * 264 + jc * 32 + quad * 8);
            frag8 av01 = *(const frag8*)(sV + m * 264 + (jc + 1) * 32 + quad * 8);
            frag8 av10 = *(const frag8*)(sV + (16 + m) * 264 + jc * 32 + quad * 8);
            frag8 av11 = *(const frag8*)(sV + (16 + m) * 264 + (jc + 1) * 32 + quad * 8);
            a0e = __builtin_amdgcn_mfma_f32_16x16x32_bf16(av00, bp0, a0e, 0, 0, 0);
            a0o = __builtin_amdgcn_mfma_f32_16x16x32_bf16(av01, bp1, a0o, 0, 0, 0);
            a1e = __builtin_amdgcn_mfma_f32_16x16x32_bf16(av10, bp0, a1e, 0, 0, 0);
            a1o = __builtin_amdgcn_mfma_f32_16x16x32_bf16(av11, bp1, a1o, 0, 0, 0);
        }
        f32x4 acc0 = a0e + a0o;
        f32x4 acc1 = a1e + a1o;
        float inv = 1.f / den;
        size_t base = ((size_t)(h * 32 + (p >> 11))) * P_TOT + (size_t)(p & 2047) * 32;
        uint4 o0, o1;
        o0.x = packhl(acc0[0] * inv); o0.y = packhl(acc0[1] * inv);
        o0.z = packhl(acc0[2] * inv); o0.w = packhl(acc0[3] * inv);
        o1.x = packhl(acc1[0] * inv); o1.y = packhl(acc1[1] * inv);
        o1.z = packhl(acc1[2] * inv); o1.w = packhl(acc1[3] * inv);
        *(uint4*)(attn_pk + base + quad * 4)      = o0;
        *(uint4*)(attn_pk + base + 16 + quad * 4) = o1;
    }
}

// ---- MFMA out-proj: out[o][q] = sum_k wout[o][k]*attn[k][q] + bias ---------
__global__ __launch_bounds__(256) void k_gemm_out(const u32* __restrict__ attn_pk,
                                                  const u16* __restrict__ w2_hi,
                                                  const u16* __restrict__ w2_lo,
                                                  const float* __restrict__ bout,
                                                  float* __restrict__ out) {
    __shared__ u16 a_hi[128 * 64], a_lo[128 * 64];   // [q'][k'] swizzled
    __shared__ u16 b_hi[128 * 64], b_lo[128 * 64];   // [o][k'] swizzled
    int t    = threadIdx.x;
    int lane = t & 63, wave = t >> 6;
    int wq = wave & 1, wo = wave >> 1;
    int m = lane & 15, quad = lane >> 4;
    int q0 = blockIdx.x * 128;
    f32x4 acc[4][4] = {};
    for (int k0 = 0; k0 < 256; k0 += 64) {
        __syncthreads();
        #pragma unroll
        for (int r = 0; r < 4; ++r) {      // A: transpose attn[k][q] -> [q][k]
            int id = t + 256 * r;
            int qq = id & 127, gsel = id >> 7;
            u32 pkk[8];
            #pragma unroll
            for (int e = 0; e < 8; ++e)
                pkk[e] = attn_pk[(size_t)(k0 + gsel * 8 + e) * P_TOT + q0 + qq];
            u32 hi4[4], lo4[4];
            #pragma unroll
            for (int e = 0; e < 4; ++e) {
                hi4[e] = __builtin_amdgcn_perm(pkk[2*e+1], pkk[2*e], 0x05040100);
                lo4[e] = __builtin_amdgcn_perm(pkk[2*e+1], pkk[2*e], 0x07060302);
            }
            int go = (gsel ^ (qq & 7)) * 8;
            *(uint4*)(a_hi + qq * 64 + go) = *(uint4*)hi4;
            *(uint4*)(a_lo + qq * 64 + go) = *(uint4*)lo4;
        }
        #pragma unroll
        for (int r = 0; r < 4; ++r) {      // B: wout planes rows 0..127
            int id  = t + 256 * r;
            int row = id >> 3, gg = id & 7;
            int go  = (gg ^ (row & 7)) * 8;
            *(uint4*)(b_hi + row * 64 + go) =
                *(const uint4*)(w2_hi + (size_t)row * 256 + k0 + gg * 8);
            *(uint4*)(b_lo + row * 64 + go) =
                *(const uint4*)(w2_lo + (size_t)row * 256 + k0 + gg * 8);
        }
        __syncthreads();
        #pragma unroll
        for (int ks = 0; ks < 2; ++ks) {
            frag8 ah[4], al[4], bh[4], bl[4];
            #pragma unroll
            for (int i = 0; i < 4; ++i) {
                int row = wq * 64 + i * 16 + m;
                int gg  = (ks * 4 + quad) ^ (row & 7);
                ah[i] = *(const frag8*)(a_hi + row * 64 + gg * 8);
                al[i] = *(const frag8*)(a_lo + row * 64 + gg * 8);
            }
            #pragma unroll
            for (int j = 0; j < 4; ++j) {
                int row = wo * 64 + j * 16 + m;
                int gg  = (ks * 4 + quad) ^ (row & 7);
                bh[j] = *(const frag8*)(b_hi + row * 64 + gg * 8);
                bl[j] = *(const frag8*)(b_lo + row * 64 + gg * 8);
            }
            #pragma unroll
            for (int i = 0; i < 4; ++i)
                #pragma unroll
                for (int j = 0; j < 4; ++j) {
                    acc[i][j] = __builtin_amdgcn_mfma_f32_16x16x32_bf16(ah[i], bh[j], acc[i][j], 0, 0, 0);
                    acc[i][j] = __builtin_amdgcn_mfma_f32_16x16x32_bf16(ah[i], bl[j], acc[i][j], 0, 0, 0);
                    acc[i][j] = __builtin_amdgcn_mfma_f32_16x16x32_bf16(al[i], bh[j], acc[i][j], 0, 0, 0);
                }
        }
    }
    #pragma unroll
    for (int j = 0; j < 4; ++j) {
        int o = wo * 64 + j * 16 + m;
        float bv = bout[o];
        #pragma unroll
        for (int i = 0; i < 4; ++i) {
            int q = q0 + wq * 64 + i * 16 + quad * 4;
            float4 v;
            v.x = acc[i][j][0] + bv; v.y = acc[i][j][1] + bv;
            v.z = acc[i][j][2] + bv; v.w = acc[i][j][3] + bv;
            *(float4*)(out + (size_t)o * P_TOT + q) = v;
        }
    }
}

extern "C" void kernel_launch(void* const* d_in, const int* in_sizes, int n_in,
                              void* d_out, int out_size, void* d_ws, size_t ws_size,
                              hipStream_t stream) {
    const float* x    = (const float*)d_in[0];
    const float* g    = (const float*)d_in[1];
    const float* b    = (const float*)d_in[2];
    const float* wqkv = (const float*)d_in[3];
    const float* wout = (const float*)d_in[4];
    const float* bout = (const float*)d_in[5];
    float* out = (float*)d_out;
    float* ws  = (float*)d_ws;

    // ws layout:
    u16*   xn_hi = (u16*)ws;                // 128*65536 u16 (bf16 hi plane)
    u16*   xn_lo = xn_hi + (size_t)128 * P_TOT;  // 128*65536 u16 (lo plane)
    float* reg1  = ws + 8388608;            // 134 MB region
    float* qpwp  = reg1;                    // gemm q-partials: 1024*8192 f32
    u32*   attn_pk = (u32*)reg1;            // k_attn output (after qpw done)
    u16*   kbf  = (u16*)(reg1 + (size_t)256 * P_TOT);  // k rows bf16, 33.5 MB
    float* aux  = ws + 41943040;
    float* pd    = aux;                     // 8192   (computed by k_pd)
    float* qpw   = pd + 8192;               // 16384  (computed by k_qpw)
    float* pdh   = qpw + 16384;             // 524288 (direct-stored, q+k)
    float* kpw   = pdh + 524288;            // 16384
    int*   idx_d = (int*)(kpw + 16384);     // 32
    int*   idx_h = idx_d + 32;              // 64
    int*   idx_w = idx_h + 64;              // 64
    u16*   kb    = (u16*)(idx_w + 64);      // 8*256*32 bf16
    u16*   vT    = kb + 8 * NJ * 32;        // 8*32*256 bf16
    u16*   qT    = vT + 8 * 32 * NJ;        // 8*65536*32 bf16 (33.5 MB)
    u16*   w_hi  = qT + (size_t)8 * P_TOT * 32;  // 512*128
    u16*   w_lo  = w_hi + 512 * 128;             // 512*128
    u16*   w2_hi = w_lo + 512 * 128;             // 128*256
    u16*   w2_lo = w2_hi + 128 * 256;            // 128*256

    k_ln<<<1024, 256, 0, stream>>>(x, g, b, xn_hi, xn_lo);
    k_wsplit<<<384, 256, 0, stream>>>(wqkv, wout, w_hi, w_lo, w2_hi, w2_lo);
    k_gemm_qkv<<<dim3(512, 4), 256, 0, stream>>>(xn_hi, xn_lo, w_hi, w_lo,
                                                 kbf, qT, pdh, qpwp);
    k_pd<<<32, 256, 0, stream>>>(pdh, pd);
    k_qpw<<<256, 256, 0, stream>>>(qpwp, qpw);
    k_topk_d<<<8, 64, 0, stream>>>(pd, idx_d);
    k_topk_h<<<8, 256, 0, stream>>>(pdh, idx_d, idx_h);
    k_probe_w<<<256, 64, 0, stream>>>(kbf, idx_d, idx_h, kpw);
    k_topk_w<<<8, 256, 0, stream>>>(qpw, kpw, idx_w);
    k_gather<<<dim3(8, 128), 64, 0, stream>>>(kbf, xn_hi, xn_lo, wqkv,
                                              idx_d, idx_h, idx_w, kb, vT);
    k_attn<<<2048, 256, 0, stream>>>(qT, kb, vT, attn_pk);
    k_gemm_out<<<512, 256, 0, stream>>>(attn_pk, w2_hi, w2_lo, bout, out);
}

// Round 14
// 329.211 us; speedup vs baseline: 1.1406x; 1.1406x over previous
//
#include <hip/hip_runtime.h>
#include <math.h>

#define P_TOT 65536   // 16*64*64 spatial positions
#define CH    128     // channels
#define NHEAD 8
#define KD    4
#define KH    8
#define KW    8
#define NJ    256     // KD*KH*KW keys per head

typedef unsigned short u16;
typedef unsigned int   u32;
typedef __attribute__((ext_vector_type(8))) short frag8;   // bf16x8 (4 VGPRs)
typedef __attribute__((ext_vector_type(4))) float f32x4;   // MFMA C/D

__device__ inline u16 bf16r(float a) {                     // RTNE round
    u32 ua = __float_as_uint(a);
    return (u16)((ua + 0x7fff + ((ua >> 16) & 1)) >> 16);
}
__device__ inline float bf16f(u16 h) {
    return __uint_as_float(((u32)h) << 16);
}
__device__ inline u32 packhl(float v) {                    // hi | lo<<16
    u16 hh = bf16r(v);
    u16 ll = bf16r(v - bf16f(hh));
    return (u32)hh | ((u32)ll << 16);
}

// ---- LayerNorm, 64p x 128c tile; emits bf16 hi/lo PLANES xn_hi/xn_lo[p][c] --
__global__ __launch_bounds__(256) void k_ln(const float* __restrict__ x,
                                            const float* __restrict__ g,
                                            const float* __restrict__ b,
                                            u16* __restrict__ xn_hi,
                                            u16* __restrict__ xn_lo) {
    __shared__ u32 buf[64 * 131];         // 33.5 KB: xt (32 KB floats) then tr
    __shared__ float red[8 * 64];
    __shared__ float stat[2 * 64];
    float* xt = (float*)buf;              // [c][pp] 128x64
    int t  = threadIdx.x;
    int p0 = blockIdx.x * 64;
    #pragma unroll
    for (int r = 0; r < 8; ++r) {         // load tile: 2048 float4 chunks
        int id = t + 256 * r;
        int c = id >> 4, q4 = id & 15;
        *(float4*)(xt + c * 64 + q4 * 4) =
            *(const float4*)(x + (size_t)c * P_TOT + p0 + q4 * 4);
    }
    __syncthreads();
    int pp = t & 63, part = t >> 6;
    float sum = 0.f, ssq = 0.f;
    for (int ci = 0; ci < 32; ++ci) {
        float v = xt[(part * 32 + ci) * 64 + pp];
        sum += v; ssq += v * v;
    }
    red[part * 64 + pp] = sum;
    red[256 + part * 64 + pp] = ssq;
    __syncthreads();
    if (t < 64) {
        float s = red[t] + red[64 + t] + red[128 + t] + red[192 + t];
        float q = red[256 + t] + red[320 + t] + red[384 + t] + red[448 + t];
        float mean = s * (1.f / CH);
        float var  = q * (1.f / CH) - mean * mean;
        stat[t] = mean;
        stat[64 + t] = 1.f / sqrtf(var + 1e-5f);
    }
    __syncthreads();
    float mean = stat[pp], inv = stat[64 + pp];
    u32 pk[32];
    for (int ci = 0; ci < 32; ++ci) {
        int c = part * 32 + ci;
        float v  = xt[c * 64 + pp];
        float xn = (v - mean) * inv * g[c] + b[c];
        pk[ci] = packhl(xn);
    }
    __syncthreads();                      // all xt reads done; reuse buf as tr
    u32* tr = buf;                        // [pp][c] stride 131
    for (int ci = 0; ci < 32; ++ci)
        tr[pp * 131 + part * 32 + ci] = pk[ci];
    __syncthreads();
    #pragma unroll
    for (int r = 0; r < 8; ++r) {         // store: 2048 chunks -> 2 planes
        int id = t + 256 * r;
        int pr = id >> 5, ch = id & 31;
        const u32* srcp = tr + pr * 131 + ch * 4;
        u32 v0 = srcp[0], v1 = srcp[1], v2 = srcp[2], v3 = srcp[3];
        uint2 hv, lv;
        hv.x = __builtin_amdgcn_perm(v1, v0, 0x05040100);   // low16 pair
        hv.y = __builtin_amdgcn_perm(v3, v2, 0x05040100);
        lv.x = __builtin_amdgcn_perm(v1, v0, 0x07060302);   // high16 pair
        lv.y = __builtin_amdgcn_perm(v3, v2, 0x07060302);
        size_t off = (size_t)(p0 + pr) * 128 + ch * 4;
        *(uint2*)(xn_hi + off) = hv;
        *(uint2*)(xn_lo + off) = lv;
    }
}

// ---- split weights into bf16 hi/lo planes ----------------------------------
__global__ __launch_bounds__(256) void k_wsplit(const float* __restrict__ wqkv,
                                                const float* __restrict__ wout,
                                                u16* __restrict__ w_hi,
                                                u16* __restrict__ w_lo,
                                                u16* __restrict__ w2_hi,
                                                u16* __restrict__ w2_lo) {
    int id = blockIdx.x * 256 + threadIdx.x;   // 0..98303
    if (id < 65536) {
        float v = wqkv[id];
        u16 hh = bf16r(v);
        w_hi[id] = hh; w_lo[id] = bf16r(v - bf16f(hh));
    } else {
        int j = id - 65536;                    // 128*256 wout
        float v = wout[j];
        u16 hh = bf16r(v);
        w2_hi[j] = hh; w2_lo[j] = bf16r(v - bf16f(hh));
    }
}

// ---- MFMA qkv GEMM + fused l2-norm + zero-atomic probes (R6, session best) --
// Closed families (measured): R5 atomics (-100us contention), R7 B-from-
// global (exposed L2 latency), R9 small tiles (+38MB real fetch), R10/R12
// bf16 k-epilogue either form (VGPR 132/136, occupancy collapse). This
// 128x128 A+B-LDS fp32-k-store shape is the verified optimum: ~74.7us,
// VGPR 104, 2 blocks/CU.
__global__ __launch_bounds__(256) void k_gemm_qkv(const u16* __restrict__ xn_hi,
                                                  const u16* __restrict__ xn_lo,
                                                  const u16* __restrict__ w_hi,
                                                  const u16* __restrict__ w_lo,
                                                  float* __restrict__ qk,
                                                  u16* __restrict__ qT,
                                                  float* __restrict__ pdh,
                                                  float* __restrict__ qpwp) {
    __shared__ u16 smem[4 * 128 * 64];    // 64 KB
    u16* a_hi = smem;
    u16* a_lo = smem + 8192;
    u16* b_hi = smem + 16384;
    u16* b_lo = smem + 24576;
    int t    = threadIdx.x;
    int lane = t & 63, wave = t >> 6;
    int wp = wave & 1, wo = wave >> 1;
    int m = lane & 15, quad = lane >> 4;
    int p0 = blockIdx.x * 128;
    int o0 = blockIdx.y * 128;
    f32x4 acc[4][4] = {};
    for (int k0 = 0; k0 < 128; k0 += 64) {
        __syncthreads();
        #pragma unroll
        for (int r = 0; r < 4; ++r) {      // 1024 granule slots per buffer
            int id  = t + 256 * r;
            int row = id >> 3, gg = id & 7;
            int gs  = gg ^ (row & 7);      // pre-swizzled source granule
            int dst = row * 64 + gg * 8;   // linear LDS dest
            size_t sa = (size_t)(p0 + row) * 128 + k0 + gs * 8;
            size_t sb = (size_t)(o0 + row) * 128 + k0 + gs * 8;
            *(uint4*)(a_hi + dst) = *(const uint4*)(xn_hi + sa);
            *(uint4*)(a_lo + dst) = *(const uint4*)(xn_lo + sa);
            *(uint4*)(b_hi + dst) = *(const uint4*)(w_hi + sb);
            *(uint4*)(b_lo + dst) = *(const uint4*)(w_lo + sb);
        }
        __syncthreads();
        #pragma unroll
        for (int ks = 0; ks < 2; ++ks) {
            frag8 ah[4], al[4], bh[4], bl[4];
            #pragma unroll
            for (int i = 0; i < 4; ++i) {
                int row = wp * 64 + i * 16 + m;
                int gg  = (ks * 4 + quad) ^ (row & 7);
                ah[i] = *(const frag8*)(a_hi + row * 64 + gg * 8);
                al[i] = *(const frag8*)(a_lo + row * 64 + gg * 8);
            }
            #pragma unroll
            for (int j = 0; j < 4; ++j) {
                int row = wo * 64 + j * 16 + m;
                int gg  = (ks * 4 + quad) ^ (row & 7);
                bh[j] = *(const frag8*)(b_hi + row * 64 + gg * 8);
                bl[j] = *(const frag8*)(b_lo + row * 64 + gg * 8);
            }
            #pragma unroll
            for (int i = 0; i < 4; ++i)
                #pragma unroll
                for (int j = 0; j < 4; ++j) {
                    acc[i][j] = __builtin_amdgcn_mfma_f32_16x16x32_bf16(ah[i], bh[j], acc[i][j], 0, 0, 0);
                    acc[i][j] = __builtin_amdgcn_mfma_f32_16x16x32_bf16(ah[i], bl[j], acc[i][j], 0, 0, 0);
                    acc[i][j] = __builtin_amdgcn_mfma_f32_16x16x32_bf16(al[i], bh[j], acc[i][j], 0, 0, 0);
                }
        }
    }
    // ---- fused l2-norm: group jg covers o rows [o0+wo*64+jg*32, +32) -------
    #pragma unroll
    for (int i = 0; i < 4; ++i) {
        #pragma unroll
        for (int jg = 0; jg < 2; ++jg) {
            f32x4 s;
            #pragma unroll
            for (int r = 0; r < 4; ++r)
                s[r] = acc[i][2 * jg][r] * acc[i][2 * jg][r]
                     + acc[i][2 * jg + 1][r] * acc[i][2 * jg + 1][r];
            #pragma unroll
            for (int mask = 1; mask <= 8; mask <<= 1) {
                s[0] += __shfl_xor(s[0], mask, 64);
                s[1] += __shfl_xor(s[1], mask, 64);
                s[2] += __shfl_xor(s[2], mask, 64);
                s[3] += __shfl_xor(s[3], mask, 64);
            }
            #pragma unroll
            for (int r = 0; r < 4; ++r) {
                float inv = 1.f / fmaxf(sqrtf(s[r]), 1e-12f);
                acc[i][2 * jg][r]     *= inv;
                acc[i][2 * jg + 1][r] *= inv;
            }
        }
    }
    // ---- fused probes (direct stores only) ---------------------------------
    int pb = blockIdx.x;
    int d  = pb >> 5;
    int hh = (2 * pb + wp) & 63;
    bool isQ = (o0 < 256);
    {
        float sj[4];
        #pragma unroll
        for (int j = 0; j < 4; ++j) {
            float s = 0.f;
            #pragma unroll
            for (int i = 0; i < 4; ++i)
                #pragma unroll
                for (int r = 0; r < 4; ++r)
                    s += fabsf(acc[i][j][r]);
            sj[j] = s;
        }
        #pragma unroll
        for (int j = 0; j < 4; ++j) {      // reduce over quad (lanes ^16,^32)
            sj[j] += __shfl_xor(sj[j], 16, 64);
            sj[j] += __shfl_xor(sj[j], 32, 64);
        }
        if (quad == 0) {
            #pragma unroll
            for (int j = 0; j < 4; ++j) {
                int o = o0 + wo * 64 + j * 16 + m;
                pdh[((size_t)o * 16 + d) * 64 + hh] = sj[j];   // unique owner
            }
        }
    }
    if (isQ) {
        // ---- qpw partial: LDS [w][ol] stride 129, wp0 writes / wp1 adds ----
        float* qw = (float*)smem;
        __syncthreads();                   // MFMA smem reads all done
        if (wp == 0) {
            #pragma unroll
            for (int j = 0; j < 4; ++j) {
                int ol = wo * 64 + j * 16 + m;
                #pragma unroll
                for (int i = 0; i < 4; ++i)
                    #pragma unroll
                    for (int r = 0; r < 4; ++r)
                        qw[(i * 16 + quad * 4 + r) * 129 + ol] = fabsf(acc[i][j][r]);
            }
        }
        __syncthreads();
        if (wp == 1) {
            #pragma unroll
            for (int j = 0; j < 4; ++j) {
                int ol = wo * 64 + j * 16 + m;
                #pragma unroll
                for (int i = 0; i < 4; ++i)
                    #pragma unroll
                    for (int r = 0; r < 4; ++r)
                        qw[(i * 16 + quad * 4 + r) * 129 + ol] += fabsf(acc[i][j][r]);
            }
        }
        __syncthreads();
        // private partial tile, coalesced store: dst[ol*64+w] = qw[w*129+ol]
        float* dstp = qpwp + ((size_t)(blockIdx.y * 512 + pb)) * 8192;
        #pragma unroll
        for (int ri = 0; ri < 32; ++ri) {
            int id = t + 256 * ri;         // id = ol*64 + w
            int ol = id >> 6, w = id & 63;
            dstp[id] = qw[w * 129 + ol];
        }
    } else {
        // ---- store normalized qk, K ROWS ONLY ------------------------------
        #pragma unroll
        for (int i = 0; i < 4; ++i) {
            int p = p0 + wp * 64 + i * 16 + quad * 4;
            #pragma unroll
            for (int j = 0; j < 4; ++j) {
                int o = o0 + wo * 64 + j * 16 + m;
                float4 v;
                v.x = acc[i][j][0]; v.y = acc[i][j][1];
                v.z = acc[i][j][2]; v.w = acc[i][j][3];
                *(float4*)(qk + (size_t)o * P_TOT + p) = v;
            }
        }
    }
    // ---- q-blocks: qT via LDS transpose + coalesced uint4 stores -----------
    if (isQ) {
        __syncthreads();                   // qw reads done; reuse smem as qtb
        u16* qtb = smem;                   // [grp][128 pl][stride 40]: 40 KB
        #pragma unroll
        for (int i = 0; i < 4; ++i)
            #pragma unroll
            for (int j = 0; j < 4; ++j) {
                int grp = wo * 2 + (j >> 1);
                int c   = (j & 1) * 16 + m;
                #pragma unroll
                for (int r = 0; r < 4; ++r) {
                    int pl = wp * 64 + i * 16 + quad * 4 + r;
                    qtb[grp * 5120 + pl * 40 + c] = bf16r(acc[i][j][r]);
                }
            }
        __syncthreads();
        int gbase = o0 >> 5;
        #pragma unroll
        for (int ri = 0; ri < 8; ++ri) {
            int id = t + 256 * ri;         // 2048 uint4 = 4grp x 128pl x 4cq
            int grp = id >> 9, rem = id & 511;
            int pl = rem >> 2, cq = rem & 3;
            uint4 v = *(const uint4*)(qtb + grp * 5120 + pl * 40 + cq * 8);
            *(uint4*)(qT + ((size_t)(gbase + grp) * P_TOT + p0 + pl) * 32 + cq * 8) = v;
        }
    }
}

// ---- pd[o][d] = sum_h pdh[o][d][h] (2 MB read, trivial) --------------------
__global__ __launch_bounds__(256) void k_pd(const float* __restrict__ pdh,
                                            float* __restrict__ pd) {
    int gid = blockIdx.x * 256 + threadIdx.x;   // 0..8191
    const float* src = pdh + (size_t)gid * 64;
    float s = 0.f;
    #pragma unroll
    for (int h = 0; h < 64; ++h) s += src[h];
    pd[gid] = s;
}

// ---- qpw[o][w] = sum_pb qpwp[part][ (o&127)*64 + w ] (33.5 MB read) --------
__global__ __launch_bounds__(256) void k_qpw(const float* __restrict__ qpwp,
                                             float* __restrict__ qpw) {
    int o = blockIdx.x;                    // 0..255
    int t = threadIdx.x;
    int w = t & 63, sub = t >> 6;
    int y = o >> 7, ol = o & 127;
    __shared__ float red[256];
    float s = 0.f;
    #pragma unroll 8
    for (int pb = sub * 128; pb < sub * 128 + 128; ++pb)
        s += qpwp[((size_t)(y * 512 + pb)) * 8192 + ol * 64 + w];
    red[t] = s;
    __syncthreads();
    if (t < 64) qpw[o * 64 + w] = red[w] + red[64 + w] + red[128 + w] + red[192 + w];
}

// ---------------- top-k kernels ----------------
__global__ __launch_bounds__(64) void k_topk_d(const float* __restrict__ pd,
                                               int* __restrict__ idx_d) {
    int h = blockIdx.x, t = threadIdx.x;
    __shared__ float sc[16];
    if (t < 16) {
        float s = 0.f;
        for (int c = 0; c < 32; ++c)
            s += pd[(h * 32 + c) * 16 + t] * pd[(256 + h * 32 + c) * 16 + t];
        sc[t] = s;
    }
    __syncthreads();
    if (t == 0) {
        bool used[16] = {};
        for (int r = 0; r < KD; ++r) {
            int best = 0; float bv = -1e30f;
            for (int i = 0; i < 16; ++i)
                if (!used[i] && sc[i] > bv) { bv = sc[i]; best = i; }
            used[best] = true;
            idx_d[h * KD + r] = best;
        }
    }
}

__global__ __launch_bounds__(256) void k_topk_h(const float* __restrict__ pdh,
                                                const int* __restrict__ idx_d,
                                                int* __restrict__ idx_h) {
    int h = blockIdx.x, t = threadIdx.x;
    int tq = t & 63, cg = t >> 6;
    __shared__ float sc2[4][64];
    __shared__ float sc[64];
    int ds[KD];
    #pragma unroll
    for (int i = 0; i < KD; ++i) ds[i] = idx_d[h * KD + i];
    float partial = 0.f;
    for (int ci = 0; ci < 8; ++ci) {
        int c  = cg * 8 + ci;
        int oq = h * 32 + c, ok = 256 + h * 32 + c;
        float qp = 0.f;                    // qph inline: sum pdh over all d
        #pragma unroll
        for (int dq = 0; dq < 16; ++dq)
            qp += pdh[((size_t)oq * 16 + dq) * 64 + tq];
        float kp = 0.f;
        #pragma unroll
        for (int i = 0; i < KD; ++i) kp += pdh[((size_t)ok * 16 + ds[i]) * 64 + tq];
        partial += qp * kp;
    }
    sc2[cg][tq] = partial;
    __syncthreads();
    if (t < 64) sc[t] = sc2[0][t] + sc2[1][t] + sc2[2][t] + sc2[3][t];
    __syncthreads();
    if (t == 0) {
        bool used[64] = {};
        for (int r = 0; r < KH; ++r) {
            int best = 0; float bv = -1e30f;
            for (int i = 0; i < 64; ++i)
                if (!used[i] && sc[i] > bv) { bv = sc[i]; best = i; }
            used[best] = true;
            idx_h[h * KH + r] = best;
        }
    }
}

__global__ __launch_bounds__(64) void k_probe_w(const float* __restrict__ qk,
                                                const int* __restrict__ idx_d,
                                                const int* __restrict__ idx_h,
                                                float* __restrict__ kpw) {
    int o2 = blockIdx.x;
    int w  = threadIdx.x;
    int h  = o2 >> 5;
    const float* src = qk + (size_t)(256 + o2) * P_TOT;
    float s = 0.f;
    for (int i = 0; i < KD; ++i) {
        int pb = idx_d[h * KD + i] * 4096;
        for (int j = 0; j < KH; ++j)
            s += fabsf(src[pb + idx_h[h * KH + j] * 64 + w]);
    }
    kpw[o2 * 64 + w] = s;
}

__global__ __launch_bounds__(256) void k_topk_w(const float* __restrict__ qpw,
                                                const float* __restrict__ kpw,
                                                int* __restrict__ idx_w) {
    int h = blockIdx.x, t = threadIdx.x;
    int tq = t & 63, cg = t >> 6;
    __shared__ float sc2[4][64];
    __shared__ float sc[64];
    float partial = 0.f;
    for (int ci = 0; ci < 8; ++ci) {
        int c  = cg * 8 + ci;
        int oq = h * 32 + c;
        partial += qpw[oq * 64 + tq] * kpw[(h * 32 + c) * 64 + tq];
    }
    sc2[cg][tq] = partial;
    __syncthreads();
    if (t < 64) sc[t] = sc2[0][t] + sc2[1][t] + sc2[2][t] + sc2[3][t];
    __syncthreads();
    if (t == 0) {
        bool used[64] = {};
        for (int r = 0; r < KW; ++r) {
            int best = 0; float bv = -1e30f;
            for (int i = 0; i < 64; ++i)
                if (!used[i] && sc[i] > bv) { bv = sc[i]; best = i; }
            used[best] = true;
            idx_w[h * KW + r] = best;
        }
    }
}

// ------- gather pruned k (bf16 [h][j][32]) + recompute v (bf16 [h][c][256]) ---
// vT j-axis is stored PERMUTED so k_attn's PV B-operand comes straight from
// the QK^T result registers. Mapping: value for key slot j lands at
// pos = (j&0xE0) | ((j&0x0C)<<1) | ((j&0x10)>>2) | (j&3).
__global__ __launch_bounds__(64) void k_gather(const float* __restrict__ qk,
                                               const u16* __restrict__ xn_hi,
                                               const u16* __restrict__ xn_lo,
                                               const float* __restrict__ wqkv,
                                               const int* __restrict__ idx_d,
                                               const int* __restrict__ idx_h,
                                               const int* __restrict__ idx_w,
                                               u16* __restrict__ kb,
                                               u16* __restrict__ vT) {
    int h  = blockIdx.x;          // 0..7
    int jb = blockIdx.y;          // 0..127
    int t  = threadIdx.x;         // 0..63
    int j  = jb * 2 + (t >> 5);
    int c  = t & 31;
    int di = j >> 6, hi = (j >> 3) & 7, wi = j & 7;
    int p  = idx_d[h * KD + di] * 4096 + idx_h[h * KH + hi] * 64 + idx_w[h * KW + wi];
    kb[(h * NJ + j) * 32 + c] = bf16r(qk[(size_t)(256 + h * 32 + c) * P_TOT + p]);
    const float* wr = wqkv + (512 + h * 32 + c) * CH;
    const u16* xh = xn_hi + (size_t)p * 128;
    const u16* xl = xn_lo + (size_t)p * 128;
    float acc = 0.f;
    for (int cc = 0; cc < CH; ++cc) {
        float v = bf16f(xh[cc]) + bf16f(xl[cc]);
        acc += wr[cc] * v;
    }
    int pos = (j & 0xE0) | ((j & 0x0C) << 1) | ((j & 0x10) >> 2) | (j & 3);
    vT[((size_t)h * 32 + c) * NJ + pos] = bf16r(acc);
}

// ------- MFMA flash attention, R2: K/V staged in LDS, reused 16x ------------
__device__ inline frag8 mk_frag(uint2 a, uint2 b) {
    union { u32 u[4]; frag8 f; } v;
    v.u[0] = a.x; v.u[1] = a.y; v.u[2] = b.x; v.u[3] = b.y;
    return v.f;
}

__global__ __launch_bounds__(256) void k_attn(const u16* __restrict__ qT,
                                              const u16* __restrict__ kb,
                                              const u16* __restrict__ vT,
                                              u32* __restrict__ attn_pk) {
    __shared__ u16 sK[256 * 32];        // [j][c] linear, 16 KB
    __shared__ u16 sV[32 * 264];        // [row][pos], stride 264 u16, 16.5 KB
    int h    = blockIdx.x >> 8;         // 2048 blocks: 8 heads x 256 chunks
    int pc   = blockIdx.x & 255;
    int wave = threadIdx.x >> 6;
    int lane = threadIdx.x & 63;
    int m    = lane & 15;
    int quad = lane >> 4;
    int t    = threadIdx.x;

    int qbase = pc * 256 + wave * 64;   // this wave's 64 queries
    frag8 bq[4];
    #pragma unroll
    for (int i = 0; i < 4; ++i)
        bq[i] = *(const frag8*)(qT + ((size_t)h * P_TOT + qbase + i * 16 + m) * 32 + quad * 8);

    const uint4* kg  = (const uint4*)(kb + (size_t)h * NJ * 32);
    uint4*       sKg = (uint4*)sK;
    #pragma unroll
    for (int r = 0; r < 4; ++r)
        sKg[t + 256 * r] = kg[t + 256 * r];
    const uint4* vg = (const uint4*)(vT + (size_t)h * 32 * NJ);
    #pragma unroll
    for (int r = 0; r < 4; ++r) {
        int g2 = t + 256 * r;
        int row = g2 >> 5, col = g2 & 31;
        *(uint4*)(sV + row * 264 + col * 8) = vg[g2];
    }
    __syncthreads();

    f32x4 zero = {0.f, 0.f, 0.f, 0.f};
    #pragma unroll
    for (int tile = 0; tile < 4; ++tile) {
        int p = qbase + tile * 16 + m;
        float den = 0.f;
        uint2 pk[16];
        #pragma unroll
        for (int tt = 0; tt < 16; ++tt) {
            frag8 ak = *(const frag8*)(sK + (tt * 16 + m) * 32 + quad * 8);
            f32x4 st = __builtin_amdgcn_mfma_f32_16x16x32_bf16(ak, bq[tile], zero, 0, 0, 0);
            float e0 = __expf(st[0]);
            float e1 = __expf(st[1]);
            float e2 = __expf(st[2]);
            float e3 = __expf(st[3]);
            den += (e0 + e1) + (e2 + e3);
            pk[tt].x = __builtin_amdgcn_perm(__float_as_uint(e1), __float_as_uint(e0), 0x07060302);
            pk[tt].y = __builtin_amdgcn_perm(__float_as_uint(e3), __float_as_uint(e2), 0x07060302);
        }
        den += __shfl_xor(den, 16, 64);
        den += __shfl_xor(den, 32, 64);

        f32x4 a0e = zero, a0o = zero, a1e = zero, a1o = zero;
        #pragma unroll
        for (int jc = 0; jc < 8; jc += 2) {
            frag8 bp0  = mk_frag(pk[2 * jc],     pk[2 * jc + 1]);
            frag8 bp1  = mk_frag(pk[2 * jc + 2], pk[2 * jc + 3]);
            frag8 av00 = *(const frag8*)(sV + m * 264 + jc * 32 + quad * 8);
            frag8 av01 = *(const frag8*)(sV + m * 264 + (jc + 1) * 32 + quad * 8);
            frag8 av10 = *(const frag8*)(sV + (16 + m) * 264 + jc * 32 + quad * 8);
            frag8 av11 = *(const frag8*)(sV + (16 + m) * 264 + (jc + 1) * 32 + quad * 8);
            a0e = __builtin_amdgcn_mfma_f32_16x16x32_bf16(av00, bp0, a0e, 0, 0, 0);
            a0o = __builtin_amdgcn_mfma_f32_16x16x32_bf16(av01, bp1, a0o, 0, 0, 0);
            a1e = __builtin_amdgcn_mfma_f32_16x16x32_bf16(av10, bp0, a1e, 0, 0, 0);
            a1o = __builtin_amdgcn_mfma_f32_16x16x32_bf16(av11, bp1, a1o, 0, 0, 0);
        }
        f32x4 acc0 = a0e + a0o;
        f32x4 acc1 = a1e + a1o;
        float inv = 1.f / den;
        size_t base = ((size_t)(h * 32 + (p >> 11))) * P_TOT + (size_t)(p & 2047) * 32;
        uint4 o0, o1;
        o0.x = packhl(acc0[0] * inv); o0.y = packhl(acc0[1] * inv);
        o0.z = packhl(acc0[2] * inv); o0.w = packhl(acc0[3] * inv);
        o1.x = packhl(acc1[0] * inv); o1.y = packhl(acc1[1] * inv);
        o1.z = packhl(acc1[2] * inv); o1.w = packhl(acc1[3] * inv);
        *(uint4*)(attn_pk + base + quad * 4)      = o0;
        *(uint4*)(attn_pk + base + 16 + quad * 4) = o1;
    }
}

// ---- MFMA out-proj: out[o][q] = sum_k wout[o][k]*attn[k][q] + bias ---------
__global__ __launch_bounds__(256) void k_gemm_out(const u32* __restrict__ attn_pk,
                                                  const u16* __restrict__ w2_hi,
                                                  const u16* __restrict__ w2_lo,
                                                  const float* __restrict__ bout,
                                                  float* __restrict__ out) {
    __shared__ u16 a_hi[128 * 64], a_lo[128 * 64];   // [q'][k'] swizzled
    __shared__ u16 b_hi[128 * 64], b_lo[128 * 64];   // [o][k'] swizzled
    int t    = threadIdx.x;
    int lane = t & 63, wave = t >> 6;
    int wq = wave & 1, wo = wave >> 1;
    int m = lane & 15, quad = lane >> 4;
    int q0 = blockIdx.x * 128;
    f32x4 acc[4][4] = {};
    for (int k0 = 0; k0 < 256; k0 += 64) {
        __syncthreads();
        #pragma unroll
        for (int r = 0; r < 4; ++r) {      // A: transpose attn[k][q] -> [q][k]
            int id = t + 256 * r;
            int qq = id & 127, gsel = id >> 7;
            u32 pkk[8];
            #pragma unroll
            for (int e = 0; e < 8; ++e)
                pkk[e] = attn_pk[(size_t)(k0 + gsel * 8 + e) * P_TOT + q0 + qq];
            u32 hi4[4], lo4[4];
            #pragma unroll
            for (int e = 0; e < 4; ++e) {
                hi4[e] = __builtin_amdgcn_perm(pkk[2*e+1], pkk[2*e], 0x05040100);
                lo4[e] = __builtin_amdgcn_perm(pkk[2*e+1], pkk[2*e], 0x07060302);
            }
            int go = (gsel ^ (qq & 7)) * 8;
            *(uint4*)(a_hi + qq * 64 + go) = *(uint4*)hi4;
            *(uint4*)(a_lo + qq * 64 + go) = *(uint4*)lo4;
        }
        #pragma unroll
        for (int r = 0; r < 4; ++r) {      // B: wout planes rows 0..127
            int id  = t + 256 * r;
            int row = id >> 3, gg = id & 7;
            int go  = (gg ^ (row & 7)) * 8;
            *(uint4*)(b_hi + row * 64 + go) =
                *(const uint4*)(w2_hi + (size_t)row * 256 + k0 + gg * 8);
            *(uint4*)(b_lo + row * 64 + go) =
                *(const uint4*)(w2_lo + (size_t)row * 256 + k0 + gg * 8);
        }
        __syncthreads();
        #pragma unroll
        for (int ks = 0; ks < 2; ++ks) {
            frag8 ah[4], al[4], bh[4], bl[4];
            #pragma unroll
            for (int i = 0; i < 4; ++i) {
                int row = wq * 64 + i * 16 + m;
                int gg  = (ks * 4 + quad) ^ (row & 7);
                ah[i] = *(const frag8*)(a_hi + row * 64 + gg * 8);
                al[i] = *(const frag8*)(a_lo + row * 64 + gg * 8);
            }
            #pragma unroll
            for (int j = 0; j < 4; ++j) {
                int row = wo * 64 + j * 16 + m;
                int gg  = (ks * 4 + quad) ^ (row & 7);
                bh[j] = *(const frag8*)(b_hi + row * 64 + gg * 8);
                bl[j] = *(const frag8*)(b_lo + row * 64 + gg * 8);
            }
            #pragma unroll
            for (int i = 0; i < 4; ++i)
                #pragma unroll
                for (int j = 0; j < 4; ++j) {
                    acc[i][j] = __builtin_amdgcn_mfma_f32_16x16x32_bf16(ah[i], bh[j], acc[i][j], 0, 0, 0);
                    acc[i][j] = __builtin_amdgcn_mfma_f32_16x16x32_bf16(ah[i], bl[j], acc[i][j], 0, 0, 0);
                    acc[i][j] = __builtin_amdgcn_mfma_f32_16x16x32_bf16(al[i], bh[j], acc[i][j], 0, 0, 0);
                }
        }
    }
    #pragma unroll
    for (int j = 0; j < 4; ++j) {
        int o = wo * 64 + j * 16 + m;
        float bv = bout[o];
        #pragma unroll
        for (int i = 0; i < 4; ++i) {
            int q = q0 + wq * 64 + i * 16 + quad * 4;
            float4 v;
            v.x = acc[i][j][0] + bv; v.y = acc[i][j][1] + bv;
            v.z = acc[i][j][2] + bv; v.w = acc[i][j][3] + bv;
            *(float4*)(out + (size_t)o * P_TOT + q) = v;
        }
    }
}

extern "C" void kernel_launch(void* const* d_in, const int* in_sizes, int n_in,
                              void* d_out, int out_size, void* d_ws, size_t ws_size,
                              hipStream_t stream) {
    const float* x    = (const float*)d_in[0];
    const float* g    = (const float*)d_in[1];
    const float* b    = (const float*)d_in[2];
    const float* wqkv = (const float*)d_in[3];
    const float* wout = (const float*)d_in[4];
    const float* bout = (const float*)d_in[5];
    float* out = (float*)d_out;
    float* ws  = (float*)d_ws;

    // ws layout:
    u16*   xn_hi = (u16*)ws;                // 128*65536 u16 (bf16 hi plane)
    u16*   xn_lo = xn_hi + (size_t)128 * P_TOT;  // 128*65536 u16 (lo plane)
    float* qk   = ws + 8388608;             // k rows only (o 256..511 used)
    float* qpwp = qk;                       // q-row region reused: 1024*8192 f32
    u32*   attn_pk = (u32*)(qk + (size_t)256 * P_TOT);  // overlays k rows after gather
    float* aux  = ws + 41943040;
    float* pd    = aux;                     // 8192   (computed by k_pd)
    float* qpw   = pd + 8192;               // 16384  (computed by k_qpw)
    float* pdh   = qpw + 16384;             // 524288 (direct-stored, q+k)
    float* kpw   = pdh + 524288;            // 16384
    int*   idx_d = (int*)(kpw + 16384);     // 32
    int*   idx_h = idx_d + 32;              // 64
    int*   idx_w = idx_h + 64;              // 64
    u16*   kb    = (u16*)(idx_w + 64);      // 8*256*32 bf16
    u16*   vT    = kb + 8 * NJ * 32;        // 8*32*256 bf16
    u16*   qT    = vT + 8 * 32 * NJ;        // 8*65536*32 bf16 (33.5 MB)
    u16*   w_hi  = qT + (size_t)8 * P_TOT * 32;  // 512*128
    u16*   w_lo  = w_hi + 512 * 128;             // 512*128
    u16*   w2_hi = w_lo + 512 * 128;             // 128*256
    u16*   w2_lo = w2_hi + 128 * 256;            // 128*256

    k_ln<<<1024, 256, 0, stream>>>(x, g, b, xn_hi, xn_lo);
    k_wsplit<<<384, 256, 0, stream>>>(wqkv, wout, w_hi, w_lo, w2_hi, w2_lo);
    k_gemm_qkv<<<dim3(512, 4), 256, 0, stream>>>(xn_hi, xn_lo, w_hi, w_lo,
                                                 qk, qT, pdh, qpwp);
    k_pd<<<32, 256, 0, stream>>>(pdh, pd);
    k_qpw<<<256, 256, 0, stream>>>(qpwp, qpw);
    k_topk_d<<<8, 64, 0, stream>>>(pd, idx_d);
    k_topk_h<<<8, 256, 0, stream>>>(pdh, idx_d, idx_h);
    k_probe_w<<<256, 64, 0, stream>>>(qk, idx_d, idx_h, kpw);
    k_topk_w<<<8, 256, 0, stream>>>(qpw, kpw, idx_w);
    k_gather<<<dim3(8, 128), 64, 0, stream>>>(qk, xn_hi, xn_lo, wqkv,
                                              idx_d, idx_h, idx_w, kb, vT);
    k_attn<<<2048, 256, 0, stream>>>(qT, kb, vT, attn_pk);
    k_gemm_out<<<512, 256, 0, stream>>>(attn_pk, w2_hi, w2_lo, bout, out);
}